// Round 3
// baseline (18.991 us; speedup 1.0000x reference)
//
#include <hip/hip_runtime.h>

// LogLinearModel: logits[b,j,v] = bias[v] + sum_{p=0..3} W[v, x[b,j-4+p]*4 + p]  (j>=4)
//                 logits[b,j,v] = bias[v]                                        (j<4)
// B=32, L=4096, N_SYM=64, D=256. Output fp32 (B,L,64) = 32MB -> store-BW-bound.
// bf16 LDS table (32KB) -> 4 blocks/CU, 1024-block grid, NT stores.

#define NSYM   64
#define CTX    4
#define DFEAT  256
#define LSEQ   4096
#define BATCH  32
#define NPOS   (BATCH * LSEQ)      // 131072 positions
#define IPW    8                   // iterations per wave (4 positions each)
#define WAVES  4
#define POS_PER_BLOCK (WAVES * 4 * IPW)      // 128
#define BLOCKS (NPOS / POS_PER_BLOCK)        // 1024

typedef float vfloat4 __attribute__((ext_vector_type(4)));   // native vector for NT store

static __device__ __forceinline__ unsigned f2bf(float f) {
    unsigned u = __float_as_uint(f);
    return (u + 0x7fffu + ((u >> 16) & 1u)) >> 16;   // RNE, inputs are tame
}

__global__ __launch_bounds__(256, 4)
void loglinear_kernel(const int* __restrict__ x,
                      const float* __restrict__ W,
                      const float* __restrict__ bias,
                      float* __restrict__ out) {
    // Wt bf16, transposed + XOR-swizzled: row d (0..255) = 64 bf16 = 32 u32 = 128B.
    // u32 at [d*32 + ((q^(d&15))<<1) + h] holds bf16 pair (v=4q+2h, v=4q+2h+1).
    __shared__ unsigned int wt[DFEAT * 32];   // 32 KB

    const int t = threadIdx.x;

    // ---- stage W (64x256 f32 row-major) -> bf16 transposed LDS ----
    {
        const int vp    = t & 31;      // v-pair: v = 2vp, 2vp+1
        const int chunk = t >> 5;      // 0..7 -> d-range
        const int q = vp >> 1, h = vp & 1;
        #pragma unroll
        for (int it = 0; it < 8; ++it) {
            const int d0 = (chunk * 8 + it) * 4;
            const float4 a = *reinterpret_cast<const float4*>(W + (2*vp)     * DFEAT + d0);
            const float4 b = *reinterpret_cast<const float4*>(W + (2*vp + 1) * DFEAT + d0);
            const float av[4] = {a.x, a.y, a.z, a.w};
            const float bv[4] = {b.x, b.y, b.z, b.w};
            #pragma unroll
            for (int k = 0; k < 4; ++k) {
                const int d = d0 + k;
                wt[d*32 + (((q ^ (d & 15)) << 1) + h)] = f2bf(av[k]) | (f2bf(bv[k]) << 16);
            }
        }
    }
    __syncthreads();

    const int lane = t & 63;
    const int wave = t >> 6;
    const int g = lane >> 4;      // position sub-index (0..3)
    const int q = lane & 15;      // v-quad (float4 of outputs)

    const float4 bq = reinterpret_cast<const float4*>(bias)[q];
    const vfloat4 b4 = {bq.x, bq.y, bq.z, bq.w};

    const int gw = blockIdx.x * WAVES + wave;   // 0..4095
    const int i0 = gw * IPW;
    vfloat4* __restrict__ out4 = reinterpret_cast<vfloat4*>(out);

    #pragma unroll
    for (int ii = 0; ii < IPW; ++ii) {
        const int P  = (i0 + ii) * 4 + g;       // global position
        const int bi = P >> 12;                 // / LSEQ
        const int j  = P & (LSEQ - 1);
        vfloat4 acc = b4;
        if (j >= CTX) {
            const int* xp = x + bi * LSEQ + j - CTX;
            #pragma unroll
            for (int p = 0; p < CTX; ++p) {
                const int c = xp[p] * 4 + p;    // W column, 0..255
                const uint2 wp = *reinterpret_cast<const uint2*>(
                    &wt[c*32 + ((q ^ (c & 15)) << 1)]);
                acc.x += __uint_as_float(wp.x << 16);
                acc.y += __uint_as_float(wp.x & 0xffff0000u);
                acc.z += __uint_as_float(wp.y << 16);
                acc.w += __uint_as_float(wp.y & 0xffff0000u);
            }
        }
        __builtin_nontemporal_store(acc, &out4[(size_t)P * 16 + q]);  // 1KB/wave, coalesced
    }
}

extern "C" void kernel_launch(void* const* d_in, const int* in_sizes, int n_in,
                              void* d_out, int out_size, void* d_ws, size_t ws_size,
                              hipStream_t stream) {
    const int*   x   = (const int*)d_in[0];
    const float* W   = (const float*)d_in[1];
    const float* b   = (const float*)d_in[2];
    float*       out = (float*)d_out;

    hipLaunchKernelGGL(loglinear_kernel, dim3(BLOCKS), dim3(256), 0, stream,
                       x, W, b, out);
}

// Round 4
// 16.621 us; speedup vs baseline: 1.1426x; 1.1426x over previous
//
#include <hip/hip_runtime.h>

// LogLinearModel: logits[b,j,v] = bias[v] + sum_{p=0..3} W[v, x[b,j-4+p]*4 + p]  (j>=4)
//                 logits[b,j,v] = bias[v]                                        (j<4)
// B=32, L=4096, N_SYM=64, D=256. Output fp32 (B,L,64) = 32MB -> store-BW-bound.
//
// R4: main loop touches global memory ONLY with stores (x staged in LDS) so the
// vmcnt queue is never waited on mid-loop -> stores free-flow like a fill kernel.

#define NSYM   64
#define CTX    4
#define DFEAT  256
#define LSEQ   4096
#define NPOS   (32 * LSEQ)          // 131072 positions
#define IPW    16                   // iterations per wave (4 positions each)
#define WAVES  4
#define POS_PER_BLOCK (WAVES * 64)  // 256 positions/block
#define BLOCKS (NPOS / POS_PER_BLOCK)   // 512

typedef float vfloat4 __attribute__((ext_vector_type(4)));

static __device__ __forceinline__ unsigned f2bf(float f) {
    unsigned u = __float_as_uint(f);
    return (u + 0x7fffu + ((u >> 16) & 1u)) >> 16;   // RNE
}

__global__ __launch_bounds__(256, 2)
void loglinear_kernel(const int* __restrict__ x,
                      const float* __restrict__ W,
                      const float* __restrict__ bias,
                      float* __restrict__ out) {
    // Wt bf16, transposed + rotate-swizzled: row c (0..255) = 32 u32 = 128B.
    // u32 word [c*32 + ((q+c)&15)*2 + h] holds bf16 pair (v=4q+2h, v=4q+2h+1).
    __shared__ unsigned int wt[DFEAT * 32];          // 32 KB
    __shared__ int          xs[POS_PER_BLOCK + CTX]; // 260 ints

    const int t  = threadIdx.x;
    const int PB = blockIdx.x * POS_PER_BLOCK;       // block's first position
    const int jb = PB & (LSEQ - 1);                  // j at block start (blocks never straddle batches)

    // ---- stage x chunk (coalesced, one-time) ----
    for (int k = t; k < POS_PER_BLOCK + CTX; k += 256) {
        xs[k] = (jb == 0 && k < CTX) ? 0 : x[PB - CTX + k];
    }

    // ---- stage W (64x256 f32 row-major) -> bf16 transposed LDS ----
    {
        const int vp    = t & 31;      // v-pair: v = 2vp, 2vp+1
        const int chunk = t >> 5;      // 0..7
        const int q = vp >> 1, h = vp & 1;
        #pragma unroll
        for (int it = 0; it < 8; ++it) {
            const int d0 = (chunk * 8 + it) * 4;
            const float4 a = *reinterpret_cast<const float4*>(W + (2*vp)     * DFEAT + d0);
            const float4 b = *reinterpret_cast<const float4*>(W + (2*vp + 1) * DFEAT + d0);
            const float av[4] = {a.x, a.y, a.z, a.w};
            const float bv[4] = {b.x, b.y, b.z, b.w};
            #pragma unroll
            for (int k = 0; k < 4; ++k) {
                const int d = d0 + k;
                wt[d*32 + ((((q + d) & 15) << 1) + h)] = f2bf(av[k]) | (f2bf(bv[k]) << 16);
            }
        }
    }
    __syncthreads();

    const int lane = t & 63;
    const int wave = t >> 6;
    const int g = lane >> 4;      // position sub-index within wave-iter (0..3)
    const int q = lane & 15;      // v-quad (float4 of outputs)

    const float4 bq = reinterpret_cast<const float4*>(bias)[q];
    const vfloat4 b4 = {bq.x, bq.y, bq.z, bq.w};

    const int jbase = wave * 64;                   // wave's first position within block
    vfloat4* __restrict__ out4 = reinterpret_cast<vfloat4*>(out);
    const size_t outbase = (size_t)PB * 16 + q;    // float4 units

    #pragma unroll
    for (int ii = 0; ii < IPW; ++ii) {
        const int jloc = jbase + ii * 4 + g;       // position within block
        vfloat4 acc = b4;
        if (jb + jloc >= CTX) {                    // j >= 4
            #pragma unroll
            for (int p = 0; p < CTX; ++p) {
                const int c = xs[jloc + p] * 4 + p;            // W column, 0..255
                const uint2 wp = *reinterpret_cast<const uint2*>(
                    &wt[c * 32 + (((q + c) & 15) << 1)]);
                acc.x += __uint_as_float(wp.x << 16);
                acc.y += __uint_as_float(wp.x & 0xffff0000u);
                acc.z += __uint_as_float(wp.y << 16);
                acc.w += __uint_as_float(wp.y & 0xffff0000u);
            }
        }
        out4[outbase + (size_t)jloc * 16] = acc;   // wave: contiguous 1KB, vmcnt never waited
    }
}

extern "C" void kernel_launch(void* const* d_in, const int* in_sizes, int n_in,
                              void* d_out, int out_size, void* d_ws, size_t ws_size,
                              hipStream_t stream) {
    const int*   x   = (const int*)d_in[0];
    const float* W   = (const float*)d_in[1];
    const float* b   = (const float*)d_in[2];
    float*       out = (float*)d_out;

    hipLaunchKernelGGL(loglinear_kernel, dim3(BLOCKS), dim3(256), 0, stream,
                       x, W, b, out);
}